// Round 1
// baseline (62344.006 us; speedup 1.0000x reference)
//
#include <hip/hip_runtime.h>
#include <hip/hip_runtime_api.h>
#include <math.h>

// ESN: x_{t+1} = tanh(w_in * u_t + W @ x_t);  out[t-200] = dot(w_eff, x_{t+1})
// w_eff[mask[i]] = w_out[i].
//
// Persistent cooperative kernel, 256 blocks x 1024 threads, 1 row per wave,
// double-buffered x in workspace, one grid barrier per step (sense-reversing,
// agent-scope atomics). x staged to LDS per block per step.

#define Nn 4096
#define WASHOUT_N 200
#define NBLOCKS 256
#define TPB 1024
#define ROWS_PER_BLOCK 16   // Nn / NBLOCKS
#define NWAVES 16           // TPB / 64

__global__ __launch_bounds__(256) void esn_init(
    const float* __restrict__ w_out, const int* __restrict__ mask,
    float* __restrict__ x_a, float* __restrict__ x_b,
    float* __restrict__ w_eff, unsigned int* __restrict__ bar,
    float* __restrict__ out, int out_n)
{
    int i = blockIdx.x * blockDim.x + threadIdx.x;
    if (i < Nn) {
        x_a[i] = 0.0f;
        x_b[i] = 0.0f;
        w_eff[mask[i]] = w_out[i];
        if (i < out_n) out[i] = 0.0f;
        if (i < 64) bar[i] = 0u;
    }
}

__global__ __launch_bounds__(TPB) void esn_step_all(
    const float* __restrict__ u, const float* __restrict__ W,
    const float* __restrict__ w_in, float* x_a, float* x_b,
    const float* __restrict__ w_eff, unsigned int* bar,
    float* __restrict__ out, int T)
{
    __shared__ float xs[Nn];
    __shared__ float partial[NWAVES];

    const int tid  = threadIdx.x;
    const int lane = tid & 63;
    const int wave = tid >> 6;
    const int row  = blockIdx.x * ROWS_PER_BLOCK + wave;

    const float wi = w_in[row];
    const float we = w_eff[row];

    unsigned int* bar_count = bar;        // arrival counter
    unsigned int* bar_gen   = bar + 32;   // generation (separate cache line-ish)

    float* xc = x_a;   // current state (read)
    float* xn = x_b;   // next state (write)

    const float4* wrow = (const float4*)(W + (size_t)row * Nn);

    for (int t = 0; t < T; ++t) {
        float ut = u[t];

        // stage x_t into LDS: 1024 threads x float4 = 4096 floats
        float4 v = ((const float4*)xc)[tid];
        ((float4*)xs)[tid] = v;
        __syncthreads();

        // one row per wave: dot(W[row], x)
        float acc = 0.0f;
        #pragma unroll
        for (int i = 0; i < 16; ++i) {
            float4 wv = wrow[i * 64 + lane];
            float4 xv = ((const float4*)xs)[i * 64 + lane];
            acc += wv.x * xv.x;
            acc += wv.y * xv.y;
            acc += wv.z * xv.z;
            acc += wv.w * xv.w;
        }
        #pragma unroll
        for (int off = 32; off > 0; off >>= 1)
            acc += __shfl_xor(acc, off, 64);

        if (lane == 0) {
            float xnew = tanhf(__fmaf_rn(wi, ut, acc));
            xn[row] = xnew;
            partial[wave] = we * xnew;
        }
        __syncthreads();

        // grid barrier + per-block output contribution (thread 0 only)
        if (tid == 0) {
            if (t >= WASHOUT_N) {
                float s = 0.0f;
                #pragma unroll
                for (int w2 = 0; w2 < NWAVES; ++w2) s += partial[w2];
                atomicAdd(&out[t - WASHOUT_N], s);  // fire-and-forget, device scope
            }
            __threadfence();  // release: make our xn stores device-visible
            unsigned int g = __hip_atomic_load(bar_gen, __ATOMIC_RELAXED,
                                               __HIP_MEMORY_SCOPE_AGENT);
            unsigned int a = __hip_atomic_fetch_add(bar_count, 1u, __ATOMIC_ACQ_REL,
                                                    __HIP_MEMORY_SCOPE_AGENT);
            if (a == NBLOCKS - 1) {
                __hip_atomic_store(bar_count, 0u, __ATOMIC_RELAXED,
                                   __HIP_MEMORY_SCOPE_AGENT);
                __hip_atomic_store(bar_gen, g + 1u, __ATOMIC_RELEASE,
                                   __HIP_MEMORY_SCOPE_AGENT);
            } else {
                while (__hip_atomic_load(bar_gen, __ATOMIC_RELAXED,
                                         __HIP_MEMORY_SCOPE_AGENT) == g) {
                    __builtin_amdgcn_s_sleep(2);
                }
            }
            __threadfence();  // acquire: invalidate stale cached x for next stage
        }
        __syncthreads();

        // swap buffers
        float* tmp = xc; xc = xn; xn = tmp;
    }
}

extern "C" void kernel_launch(void* const* d_in, const int* in_sizes, int n_in,
                              void* d_out, int out_size, void* d_ws, size_t ws_size,
                              hipStream_t stream)
{
    const float* u     = (const float*)d_in[0];
    const float* W     = (const float*)d_in[1];
    const float* w_in  = (const float*)d_in[2];
    const float* w_out = (const float*)d_in[3];
    const int*   mask  = (const int*)d_in[4];
    float* out = (float*)d_out;
    int T = in_sizes[0];

    char* ws = (char*)d_ws;
    float* x_a            = (float*)(ws);
    float* x_b            = (float*)(ws + 16384);
    float* w_eff          = (float*)(ws + 32768);
    unsigned int* bar     = (unsigned int*)(ws + 49152);

    hipLaunchKernelGGL(esn_init, dim3(16), dim3(256), 0, stream,
                       w_out, mask, x_a, x_b, w_eff, bar, out, out_size);

    void* args[] = { (void*)&u, (void*)&W, (void*)&w_in, (void*)&x_a, (void*)&x_b,
                     (void*)&w_eff, (void*)&bar, (void*)&out, (void*)&T };
    hipError_t err = hipLaunchCooperativeKernel((const void*)esn_step_all,
                                                dim3(NBLOCKS), dim3(TPB),
                                                args, 0, stream);
    if (err != hipSuccess) {
        // fallback: plain launch (256 blocks of 1024 threads are co-resident on
        // 256 CUs in practice)
        hipLaunchKernelGGL(esn_step_all, dim3(NBLOCKS), dim3(TPB), 0, stream,
                           u, W, w_in, x_a, x_b, w_eff, bar, out, T);
    }
}

// Round 2
// 34956.149 us; speedup vs baseline: 1.7835x; 1.7835x over previous
//
#include <hip/hip_runtime.h>
#include <hip/hip_runtime_api.h>
#include <math.h>

// ESN: x_{t+1} = tanh(w_in * u_t + W @ x_t);  out[t-200] = dot(w_eff, x_{t+1})
//
// R2: sparse ELL (fp32 val + u16 col, cap 1024/row => 24 MB, ~3 MB/XCD, L2-resident)
//     + fence-free coherence: x exchanged via relaxed agent-scope atomics (sc1,
//     bypass L1/L2, coherent at L3); barrier arrival = RELEASE fetch_add.
//     No acquire fence => no buffer_inv => W never evicted from L2.

#define Nn 4096
#define WASHOUT_N 200
#define NBLOCKS 256
#define TPB 1024
#define ROWS_PER_BLOCK 16   // Nn / NBLOCKS
#define NWAVES 16           // TPB / 64
#define ELL_CAP 1024        // mean nnz = 819.2, sigma = 25.6; 1024 = +8 sigma

__global__ __launch_bounds__(256) void esn_init(
    const float* __restrict__ w_out, const int* __restrict__ mask,
    float* __restrict__ x_a, float* __restrict__ x_b,
    float* __restrict__ w_eff, unsigned int* __restrict__ bar,
    float* __restrict__ out, int out_n)
{
    int i = blockIdx.x * blockDim.x + threadIdx.x;
    if (i < Nn) {
        x_a[i] = 0.0f;
        x_b[i] = 0.0f;
        w_eff[mask[i]] = w_out[i];
        if (i < out_n) out[i] = 0.0f;
        if (i < 64) bar[i] = 0u;
    }
}

// One block per row: compact nonzeros of dense W row into ELL (val fp32, col u16).
__global__ __launch_bounds__(256) void build_ell(
    const float* __restrict__ W, float* __restrict__ ev,
    unsigned short* __restrict__ ec)
{
    int row = blockIdx.x;
    __shared__ unsigned int cnt;
    if (threadIdx.x == 0) cnt = 0u;
    __syncthreads();
    const float* wr = W + (size_t)row * Nn;
    size_t base = (size_t)row * ELL_CAP;
    for (int j = threadIdx.x; j < Nn; j += 256) {
        float v = wr[j];
        if (v != 0.0f) {
            unsigned int s = atomicAdd(&cnt, 1u);
            if (s < ELL_CAP) { ev[base + s] = v; ec[base + s] = (unsigned short)j; }
        }
    }
    __syncthreads();
    for (unsigned int s = cnt + threadIdx.x; s < ELL_CAP; s += 256) {
        ev[base + s] = 0.0f;
        ec[base + s] = 0;
    }
}

__global__ __launch_bounds__(TPB) void esn_step_sparse(
    const float* __restrict__ u, const float* __restrict__ w_in,
    const float* __restrict__ ev, const unsigned short* __restrict__ ec,
    float* x_a, float* x_b, const float* __restrict__ w_eff,
    unsigned int* bar, float* __restrict__ out, int T)
{
    __shared__ float xs[Nn];
    __shared__ float partial[NWAVES];

    const int tid  = threadIdx.x;
    const int lane = tid & 63;
    const int wave = tid >> 6;
    const int row  = blockIdx.x * ROWS_PER_BLOCK + wave;

    const float wi = w_in[row];
    const float we = w_eff[row];

    unsigned int* bar_count = bar;        // arrival counter
    unsigned int* bar_gen   = bar + 32;   // generation word, 128 B away

    float* xc = x_a;
    float* xn = x_b;

    const float4*  v4 = (const float4*)(ev + (size_t)row * ELL_CAP);
    const ushort4* c4 = (const ushort4*)(ec + (size_t)row * ELL_CAP);

    for (int t = 0; t < T; ++t) {
        const float ut = u[t];

        // stage x_t into LDS via coherent (agent-scope, cache-bypassing) loads
        #pragma unroll
        for (int k = 0; k < 4; ++k) {
            int idx = k * TPB + tid;
            xs[idx] = __hip_atomic_load(&xc[idx], __ATOMIC_RELAXED,
                                        __HIP_MEMORY_SCOPE_AGENT);
        }
        __syncthreads();

        // sparse dot: 16 nnz per lane as 4 x (float4 vals + ushort4 cols)
        float acc = 0.0f;
        #pragma unroll
        for (int i = 0; i < 4; ++i) {
            float4  v = v4[i * 64 + lane];
            ushort4 c = c4[i * 64 + lane];
            acc += v.x * xs[c.x];
            acc += v.y * xs[c.y];
            acc += v.z * xs[c.z];
            acc += v.w * xs[c.w];
        }
        #pragma unroll
        for (int off = 32; off > 0; off >>= 1)
            acc += __shfl_xor(acc, off, 64);

        if (lane == 0) {
            float xnew = tanhf(__fmaf_rn(wi, ut, acc));
            // coherent write-through store (visible at L3 without any fence)
            __hip_atomic_store(&xn[row], xnew, __ATOMIC_RELAXED,
                               __HIP_MEMORY_SCOPE_AGENT);
            partial[wave] = we * xnew;
        }
        __syncthreads();

        if (tid == 0) {
            if (t >= WASHOUT_N) {
                float s = 0.0f;
                #pragma unroll
                for (int w2 = 0; w2 < NWAVES; ++w2) s += partial[w2];
                atomicAdd(&out[t - WASHOUT_N], s);
            }
            // RELEASE arrival: orders our xn stores to the coherent point.
            // No acquire anywhere => no L2 invalidate => W stays L2-resident.
            unsigned int g = __hip_atomic_load(bar_gen, __ATOMIC_RELAXED,
                                               __HIP_MEMORY_SCOPE_AGENT);
            unsigned int a = __hip_atomic_fetch_add(bar_count, 1u, __ATOMIC_RELEASE,
                                                    __HIP_MEMORY_SCOPE_AGENT);
            if (a == NBLOCKS - 1) {
                __hip_atomic_store(bar_count, 0u, __ATOMIC_RELAXED,
                                   __HIP_MEMORY_SCOPE_AGENT);
                // RELEASE: count reset must be visible before gen bump
                __hip_atomic_store(bar_gen, g + 1u, __ATOMIC_RELEASE,
                                   __HIP_MEMORY_SCOPE_AGENT);
            } else {
                while (__hip_atomic_load(bar_gen, __ATOMIC_RELAXED,
                                         __HIP_MEMORY_SCOPE_AGENT) == g) {
                    __builtin_amdgcn_s_sleep(4);
                }
            }
            asm volatile("" ::: "memory");  // compiler barrier (no cache ops)
        }
        __syncthreads();

        float* tmp = xc; xc = xn; xn = tmp;
    }
}

// ---------------- dense fallback (round-1 path, used only if ws too small) ----
__global__ __launch_bounds__(TPB) void esn_step_dense(
    const float* __restrict__ u, const float* __restrict__ W,
    const float* __restrict__ w_in, float* x_a, float* x_b,
    const float* __restrict__ w_eff, unsigned int* bar,
    float* __restrict__ out, int T)
{
    __shared__ float xs[Nn];
    __shared__ float partial[NWAVES];
    const int tid  = threadIdx.x;
    const int lane = tid & 63;
    const int wave = tid >> 6;
    const int row  = blockIdx.x * ROWS_PER_BLOCK + wave;
    const float wi = w_in[row];
    const float we = w_eff[row];
    unsigned int* bar_count = bar;
    unsigned int* bar_gen   = bar + 32;
    float* xc = x_a;
    float* xn = x_b;
    const float4* wrow = (const float4*)(W + (size_t)row * Nn);

    for (int t = 0; t < T; ++t) {
        float ut = u[t];
        float4 v = ((const float4*)xc)[tid];
        ((float4*)xs)[tid] = v;
        __syncthreads();
        float acc = 0.0f;
        #pragma unroll
        for (int i = 0; i < 16; ++i) {
            float4 wv = wrow[i * 64 + lane];
            float4 xv = ((const float4*)xs)[i * 64 + lane];
            acc += wv.x * xv.x + wv.y * xv.y + wv.z * xv.z + wv.w * xv.w;
        }
        #pragma unroll
        for (int off = 32; off > 0; off >>= 1)
            acc += __shfl_xor(acc, off, 64);
        if (lane == 0) {
            float xnew = tanhf(__fmaf_rn(wi, ut, acc));
            xn[row] = xnew;
            partial[wave] = we * xnew;
        }
        __syncthreads();
        if (tid == 0) {
            if (t >= WASHOUT_N) {
                float s = 0.0f;
                #pragma unroll
                for (int w2 = 0; w2 < NWAVES; ++w2) s += partial[w2];
                atomicAdd(&out[t - WASHOUT_N], s);
            }
            __threadfence();
            unsigned int g = __hip_atomic_load(bar_gen, __ATOMIC_RELAXED,
                                               __HIP_MEMORY_SCOPE_AGENT);
            unsigned int a = __hip_atomic_fetch_add(bar_count, 1u, __ATOMIC_ACQ_REL,
                                                    __HIP_MEMORY_SCOPE_AGENT);
            if (a == NBLOCKS - 1) {
                __hip_atomic_store(bar_count, 0u, __ATOMIC_RELAXED,
                                   __HIP_MEMORY_SCOPE_AGENT);
                __hip_atomic_store(bar_gen, g + 1u, __ATOMIC_RELEASE,
                                   __HIP_MEMORY_SCOPE_AGENT);
            } else {
                while (__hip_atomic_load(bar_gen, __ATOMIC_RELAXED,
                                         __HIP_MEMORY_SCOPE_AGENT) == g) {
                    __builtin_amdgcn_s_sleep(2);
                }
            }
            __threadfence();
        }
        __syncthreads();
        float* tmp = xc; xc = xn; xn = tmp;
    }
}

extern "C" void kernel_launch(void* const* d_in, const int* in_sizes, int n_in,
                              void* d_out, int out_size, void* d_ws, size_t ws_size,
                              hipStream_t stream)
{
    const float* u     = (const float*)d_in[0];
    const float* W     = (const float*)d_in[1];
    const float* w_in  = (const float*)d_in[2];
    const float* w_out = (const float*)d_in[3];
    const int*   mask  = (const int*)d_in[4];
    float* out = (float*)d_out;
    int T = in_sizes[0];

    const size_t ev_bytes  = (size_t)Nn * ELL_CAP * sizeof(float);          // 16 MB
    const size_t ec_bytes  = (size_t)Nn * ELL_CAP * sizeof(unsigned short); // 8 MB
    const size_t aux_bytes = 3 * 16384 + 4096;
    char* ws = (char*)d_ws;

    if (ws_size >= ev_bytes + ec_bytes + aux_bytes) {
        float*          ev    = (float*)(ws);
        unsigned short* ec    = (unsigned short*)(ws + ev_bytes);
        float*          x_a   = (float*)(ws + ev_bytes + ec_bytes);
        float*          x_b   = (float*)(ws + ev_bytes + ec_bytes + 16384);
        float*          w_eff = (float*)(ws + ev_bytes + ec_bytes + 32768);
        unsigned int*   bar   = (unsigned int*)(ws + ev_bytes + ec_bytes + 49152);

        hipLaunchKernelGGL(esn_init, dim3(16), dim3(256), 0, stream,
                           w_out, mask, x_a, x_b, w_eff, bar, out, out_size);
        hipLaunchKernelGGL(build_ell, dim3(Nn), dim3(256), 0, stream, W, ev, ec);

        void* args[] = { (void*)&u, (void*)&w_in, (void*)&ev, (void*)&ec,
                         (void*)&x_a, (void*)&x_b, (void*)&w_eff, (void*)&bar,
                         (void*)&out, (void*)&T };
        hipError_t err = hipLaunchCooperativeKernel((const void*)esn_step_sparse,
                                                    dim3(NBLOCKS), dim3(TPB),
                                                    args, 0, stream);
        if (err != hipSuccess) {
            hipLaunchKernelGGL(esn_step_sparse, dim3(NBLOCKS), dim3(TPB), 0, stream,
                               u, w_in, ev, ec, x_a, x_b, w_eff, bar, out, T);
        }
    } else {
        float*        x_a   = (float*)(ws);
        float*        x_b   = (float*)(ws + 16384);
        float*        w_eff = (float*)(ws + 32768);
        unsigned int* bar   = (unsigned int*)(ws + 49152);

        hipLaunchKernelGGL(esn_init, dim3(16), dim3(256), 0, stream,
                           w_out, mask, x_a, x_b, w_eff, bar, out, out_size);
        void* args[] = { (void*)&u, (void*)&W, (void*)&w_in, (void*)&x_a,
                         (void*)&x_b, (void*)&w_eff, (void*)&bar, (void*)&out,
                         (void*)&T };
        hipError_t err = hipLaunchCooperativeKernel((const void*)esn_step_dense,
                                                    dim3(NBLOCKS), dim3(TPB),
                                                    args, 0, stream);
        if (err != hipSuccess) {
            hipLaunchKernelGGL(esn_step_dense, dim3(NBLOCKS), dim3(TPB), 0, stream,
                               u, W, w_in, x_a, x_b, w_eff, bar, out, T);
        }
    }
}

// Round 3
// 28962.167 us; speedup vs baseline: 2.1526x; 1.2070x over previous
//
#include <hip/hip_runtime.h>
#include <hip/hip_runtime_api.h>
#include <math.h>

// ESN: x_{t+1} = tanh(w_in * u_t + W @ x_t);  out[t-200] = dot(w_eff, x_{t+1})
//
// R3: - flag-array sync (per-block monotonic step flags, relaxed agent-scope
//       loads/stores only; release provided by the compiler's mandatory
//       s_waitcnt vmcnt(0) before s_barrier). Zero RMWs in the hot loop.
//     - out[] computed by a rotating block from its own LDS copy of x (plain
//       store, off the critical path) -- no atomics on out.
//     - ELL layout dealt into 16 wave-gather groups with <=2 cols per LDS
//       bank per group (2-way is free on gfx950) -> near-zero bank conflicts.

#define Nn 4096
#define WASHOUT_N 200
#define NBLOCKS 256
#define TPB 1024
#define ROWS_PER_BLOCK 16   // Nn / NBLOCKS
#define NWAVES 16           // TPB / 64
#define ELL_CAP 1024        // 16 groups x 64 lanes; mean nnz 819, +8 sigma safe
#define FLAG_STRIDE 16      // u32s -> 64 B per flag (avoid false sharing)

__global__ __launch_bounds__(256) void esn_init(
    const float* __restrict__ w_out, const int* __restrict__ mask,
    float* __restrict__ x_a, float* __restrict__ x_b,
    float* __restrict__ w_eff, unsigned int* __restrict__ flags,
    float* __restrict__ out, int out_n)
{
    int i = blockIdx.x * blockDim.x + threadIdx.x;
    if (i < Nn) {
        x_a[i] = 0.0f;
        x_b[i] = 0.0f;
        w_eff[mask[i]] = w_out[i];
        if (i < out_n) out[i] = 0.0f;
        flags[i] = 0u;   // 4096 u32 = 16 KB, covers 256 x FLAG_STRIDE
    }
}

// One block per row. Deal nonzeros into 16 gather-groups (i in 0..3, k in 0..3);
// group (i,k) is one wave-wide ds_read: lanes L read column at ELL position
// 4*(i*64+L)+k. Assign each nonzero so that each group holds <=2 (rarely 3)
// columns per LDS bank (bank = col & 31).
__global__ __launch_bounds__(256) void build_ell(
    const float* __restrict__ W, float* __restrict__ ev,
    unsigned short* __restrict__ ec)
{
    int row = blockIdx.x;
    __shared__ unsigned int bank_cnt[32];
    __shared__ unsigned int group_cnt[16];
    if (threadIdx.x < 32) bank_cnt[threadIdx.x] = 0u;
    if (threadIdx.x < 16) group_cnt[threadIdx.x] = 0u;
    __syncthreads();

    const float* wr = W + (size_t)row * Nn;
    size_t base = (size_t)row * ELL_CAP;

    // zero the whole row first (padding slots: val 0, col 0 -> broadcast, free)
    for (int s = threadIdx.x; s < ELL_CAP; s += 256) {
        ev[base + s] = 0.0f;
        ec[base + s] = 0;
    }
    __syncthreads();

    for (int j = threadIdx.x; j < Nn; j += 256) {
        float v = wr[j];
        if (v != 0.0f) {
            unsigned int b  = (unsigned int)j & 31u;
            unsigned int jb = atomicAdd(&bank_cnt[b], 1u);
            unsigned int g  = jb & 15u;         // spread this bank across groups
            unsigned int s  = 0xFFFFFFFFu;
            for (int tries = 0; tries < 16; ++tries) {
                unsigned int cand = atomicAdd(&group_cnt[g], 1u);
                if (cand < 64u) { s = cand; break; }
                g = (g + 1u) & 15u;
            }
            if (s != 0xFFFFFFFFu) {             // drops only if nnz > 1024
                unsigned int i = g >> 2, k = g & 3u;
                unsigned int pos = 4u * (i * 64u + s) + k;
                ev[base + pos] = v;
                ec[base + pos] = (unsigned short)j;
            }
        }
    }
}

__global__ __launch_bounds__(TPB) void esn_step_sparse(
    const float* __restrict__ u, const float* __restrict__ w_in,
    const float* __restrict__ ev, const unsigned short* __restrict__ ec,
    float* x_a, float* x_b, const float* __restrict__ w_eff,
    unsigned int* flags, float* __restrict__ out, int T)
{
    __shared__ float xs[Nn];
    __shared__ float dpart[NWAVES];

    const int tid  = threadIdx.x;
    const int lane = tid & 63;
    const int wave = tid >> 6;
    const int row  = blockIdx.x * ROWS_PER_BLOCK + wave;

    const float wi = w_in[row];
    // per-thread slice of w_eff for the rotating output dot
    const float we0 = w_eff[tid];
    const float we1 = w_eff[TPB + tid];
    const float we2 = w_eff[2 * TPB + tid];
    const float we3 = w_eff[3 * TPB + tid];

    float* xc = x_a;
    float* xn = x_b;

    const float4*  v4 = (const float4*)(ev + (size_t)row * ELL_CAP);
    const ushort4* c4 = (const ushort4*)(ec + (size_t)row * ELL_CAP);

    for (int t = 0; t <= T; ++t) {
        // 1. wait until every block has published X[t-1] (flags monotonic)
        if (tid < NBLOCKS) {
            const unsigned int tgt = (unsigned int)t;
            while (__hip_atomic_load(&flags[tid * FLAG_STRIDE], __ATOMIC_RELAXED,
                                     __HIP_MEMORY_SCOPE_AGENT) < tgt) {
                __builtin_amdgcn_s_sleep(1);
            }
        }
        __syncthreads();

        // 2. stage X[t-1] into LDS (coherent agent-scope loads, bypass L1/L2)
        #pragma unroll
        for (int k = 0; k < 4; ++k) {
            int idx = k * TPB + tid;
            xs[idx] = __hip_atomic_load(&xc[idx], __ATOMIC_RELAXED,
                                        __HIP_MEMORY_SCOPE_AGENT);
        }
        __syncthreads();

        // 3. row update (skip on the tail iteration t == T)
        if (t < T) {
            const float ut = u[t];
            float acc = 0.0f;
            #pragma unroll
            for (int i = 0; i < 4; ++i) {
                float4  v = v4[i * 64 + lane];
                ushort4 c = c4[i * 64 + lane];
                acc += v.x * xs[c.x];
                acc += v.y * xs[c.y];
                acc += v.z * xs[c.z];
                acc += v.w * xs[c.w];
            }
            #pragma unroll
            for (int off = 32; off > 0; off >>= 1)
                acc += __shfl_xor(acc, off, 64);

            if (lane == 0) {
                float xnew = tanhf(__fmaf_rn(wi, ut, acc));
                __hip_atomic_store(&xn[row], xnew, __ATOMIC_RELAXED,
                                   __HIP_MEMORY_SCOPE_AGENT);
            }
            // barrier drains each wave's vmcnt before s_barrier => all x
            // stores are at the coherence point before the flag is raised
            __syncthreads();
            if (tid == 0) {
                __hip_atomic_store(&flags[blockIdx.x * FLAG_STRIDE],
                                   (unsigned int)(t + 1), __ATOMIC_RELAXED,
                                   __HIP_MEMORY_SCOPE_AGENT);
            }
        }

        // 4. rotating output dot: xs holds X[t-1]; off the critical path
        //    (runs after this block's flag is already published)
        if (t >= WASHOUT_N + 1 && (t & (NBLOCKS - 1)) == blockIdx.x) {
            float d = we0 * xs[tid] + we1 * xs[TPB + tid]
                    + we2 * xs[2 * TPB + tid] + we3 * xs[3 * TPB + tid];
            #pragma unroll
            for (int off = 32; off > 0; off >>= 1)
                d += __shfl_xor(d, off, 64);
            if (lane == 0) dpart[wave] = d;
            __syncthreads();
            if (wave == 0) {
                float s = (lane < NWAVES) ? dpart[lane] : 0.0f;
                #pragma unroll
                for (int off = 8; off > 0; off >>= 1)
                    s += __shfl_xor(s, off, 64);
                if (lane == 0) out[t - WASHOUT_N - 1] = s;
            }
        }

        float* tmp = xc; xc = xn; xn = tmp;
    }
}

// ---------------- dense fallback (only if ws too small for ELL) -------------
__global__ __launch_bounds__(TPB) void esn_step_dense(
    const float* __restrict__ u, const float* __restrict__ W,
    const float* __restrict__ w_in, float* x_a, float* x_b,
    const float* __restrict__ w_eff, unsigned int* bar,
    float* __restrict__ out, int T)
{
    __shared__ float xs[Nn];
    __shared__ float partial[NWAVES];
    const int tid  = threadIdx.x;
    const int lane = tid & 63;
    const int wave = tid >> 6;
    const int row  = blockIdx.x * ROWS_PER_BLOCK + wave;
    const float wi = w_in[row];
    const float we = w_eff[row];
    unsigned int* bar_count = bar;
    unsigned int* bar_gen   = bar + 32;
    float* xc = x_a;
    float* xn = x_b;
    const float4* wrow = (const float4*)(W + (size_t)row * Nn);

    for (int t = 0; t < T; ++t) {
        float ut = u[t];
        float4 v = ((const float4*)xc)[tid];
        ((float4*)xs)[tid] = v;
        __syncthreads();
        float acc = 0.0f;
        #pragma unroll
        for (int i = 0; i < 16; ++i) {
            float4 wv = wrow[i * 64 + lane];
            float4 xv = ((const float4*)xs)[i * 64 + lane];
            acc += wv.x * xv.x + wv.y * xv.y + wv.z * xv.z + wv.w * xv.w;
        }
        #pragma unroll
        for (int off = 32; off > 0; off >>= 1)
            acc += __shfl_xor(acc, off, 64);
        if (lane == 0) {
            float xnew = tanhf(__fmaf_rn(wi, ut, acc));
            xn[row] = xnew;
            partial[wave] = we * xnew;
        }
        __syncthreads();
        if (tid == 0) {
            if (t >= WASHOUT_N) {
                float s = 0.0f;
                #pragma unroll
                for (int w2 = 0; w2 < NWAVES; ++w2) s += partial[w2];
                atomicAdd(&out[t - WASHOUT_N], s);
            }
            __threadfence();
            unsigned int g = __hip_atomic_load(bar_gen, __ATOMIC_RELAXED,
                                               __HIP_MEMORY_SCOPE_AGENT);
            unsigned int a = __hip_atomic_fetch_add(bar_count, 1u, __ATOMIC_ACQ_REL,
                                                    __HIP_MEMORY_SCOPE_AGENT);
            if (a == NBLOCKS - 1) {
                __hip_atomic_store(bar_count, 0u, __ATOMIC_RELAXED,
                                   __HIP_MEMORY_SCOPE_AGENT);
                __hip_atomic_store(bar_gen, g + 1u, __ATOMIC_RELEASE,
                                   __HIP_MEMORY_SCOPE_AGENT);
            } else {
                while (__hip_atomic_load(bar_gen, __ATOMIC_RELAXED,
                                         __HIP_MEMORY_SCOPE_AGENT) == g) {
                    __builtin_amdgcn_s_sleep(2);
                }
            }
            __threadfence();
        }
        __syncthreads();
        float* tmp = xc; xc = xn; xn = tmp;
    }
}

extern "C" void kernel_launch(void* const* d_in, const int* in_sizes, int n_in,
                              void* d_out, int out_size, void* d_ws, size_t ws_size,
                              hipStream_t stream)
{
    const float* u     = (const float*)d_in[0];
    const float* W     = (const float*)d_in[1];
    const float* w_in  = (const float*)d_in[2];
    const float* w_out = (const float*)d_in[3];
    const int*   mask  = (const int*)d_in[4];
    float* out = (float*)d_out;
    int T = in_sizes[0];

    const size_t ev_bytes  = (size_t)Nn * ELL_CAP * sizeof(float);          // 16 MB
    const size_t ec_bytes  = (size_t)Nn * ELL_CAP * sizeof(unsigned short); // 8 MB
    const size_t aux_bytes = 4 * 16384;
    char* ws = (char*)d_ws;

    if (ws_size >= ev_bytes + ec_bytes + aux_bytes) {
        float*          ev    = (float*)(ws);
        unsigned short* ec    = (unsigned short*)(ws + ev_bytes);
        float*          x_a   = (float*)(ws + ev_bytes + ec_bytes);
        float*          x_b   = (float*)(ws + ev_bytes + ec_bytes + 16384);
        float*          w_eff = (float*)(ws + ev_bytes + ec_bytes + 32768);
        unsigned int*   flags = (unsigned int*)(ws + ev_bytes + ec_bytes + 49152);

        hipLaunchKernelGGL(esn_init, dim3(16), dim3(256), 0, stream,
                           w_out, mask, x_a, x_b, w_eff, flags, out, out_size);
        hipLaunchKernelGGL(build_ell, dim3(Nn), dim3(256), 0, stream, W, ev, ec);

        void* args[] = { (void*)&u, (void*)&w_in, (void*)&ev, (void*)&ec,
                         (void*)&x_a, (void*)&x_b, (void*)&w_eff, (void*)&flags,
                         (void*)&out, (void*)&T };
        hipError_t err = hipLaunchCooperativeKernel((const void*)esn_step_sparse,
                                                    dim3(NBLOCKS), dim3(TPB),
                                                    args, 0, stream);
        if (err != hipSuccess) {
            hipLaunchKernelGGL(esn_step_sparse, dim3(NBLOCKS), dim3(TPB), 0, stream,
                               u, w_in, ev, ec, x_a, x_b, w_eff, flags, out, T);
        }
    } else {
        float*        x_a   = (float*)(ws);
        float*        x_b   = (float*)(ws + 16384);
        float*        w_eff = (float*)(ws + 32768);
        unsigned int* bar   = (unsigned int*)(ws + 49152);

        hipLaunchKernelGGL(esn_init, dim3(16), dim3(256), 0, stream,
                           w_out, mask, x_a, x_b, w_eff, bar, out, out_size);
        void* args[] = { (void*)&u, (void*)&W, (void*)&w_in, (void*)&x_a,
                         (void*)&x_b, (void*)&w_eff, (void*)&bar, (void*)&out,
                         (void*)&T };
        hipError_t err = hipLaunchCooperativeKernel((const void*)esn_step_dense,
                                                    dim3(NBLOCKS), dim3(TPB),
                                                    args, 0, stream);
        if (err != hipSuccess) {
            hipLaunchKernelGGL(esn_step_dense, dim3(NBLOCKS), dim3(TPB), 0, stream,
                               u, W, w_in, x_a, x_b, w_eff, bar, out, T);
        }
    }
}

// Round 4
// 18217.703 us; speedup vs baseline: 3.4222x; 1.5898x over previous
//
#include <hip/hip_runtime.h>
#include <hip/hip_runtime_api.h>
#include <math.h>

// ESN: x_{t+1} = tanh(w_in * u_t + W @ x_t);  out[t-200] = dot(w_eff, x_{t+1})
//
// R4: single-hop coherence. Each state element is a tagged 64-bit word
//     (fp32 value | step tag) stored once with a relaxed agent-scope 8-byte
//     atomic. Readers poll the words directly -- no flags, no fences, no
//     ordering chain: atomicity of the word carries the dependency.
//     ELL matrix (16 vals + 16 cols per thread) hoisted into registers once;
//     the hot loop touches only: tagged-x poll loads, LDS, one 8B store.

#define Nn 4096
#define WASHOUT_N 200
#define NBLOCKS 256
#define TPB 1024
#define ROWS_PER_BLOCK 16   // Nn / NBLOCKS
#define NWAVES 16           // TPB / 64
#define ELL_CAP 1024        // 16 gather groups x 64 lanes; mean nnz 819

typedef unsigned long long u64t;

__global__ __launch_bounds__(256) void esn_init(
    const float* __restrict__ w_out, const int* __restrict__ mask,
    u64t* __restrict__ xp_a, u64t* __restrict__ xp_b,
    float* __restrict__ w_eff, float* __restrict__ out, int out_n)
{
    int i = blockIdx.x * blockDim.x + threadIdx.x;
    if (i < Nn) {
        xp_a[i] = 0ull;                 // value 0.0f, tag 0  (= x_0)
        xp_b[i] = 0ull;                 // tag 0 != 1, so step-0 writes are awaited
        w_eff[mask[i]] = w_out[i];
        if (i < out_n) out[i] = 0.0f;
    }
}

// One block per row. Deal nonzeros into 16 gather-groups; each group is one
// wave-wide LDS gather. Keep <=2 cols per LDS bank per group (2-way is free).
__global__ __launch_bounds__(256) void build_ell(
    const float* __restrict__ W, float* __restrict__ ev,
    unsigned short* __restrict__ ec)
{
    int row = blockIdx.x;
    __shared__ unsigned int bank_cnt[32];
    __shared__ unsigned int group_cnt[16];
    if (threadIdx.x < 32) bank_cnt[threadIdx.x] = 0u;
    if (threadIdx.x < 16) group_cnt[threadIdx.x] = 0u;
    __syncthreads();

    const float* wr = W + (size_t)row * Nn;
    size_t base = (size_t)row * ELL_CAP;

    for (int s = threadIdx.x; s < ELL_CAP; s += 256) {
        ev[base + s] = 0.0f;
        ec[base + s] = 0;               // col 0 -> broadcast, free
    }
    __syncthreads();

    for (int j = threadIdx.x; j < Nn; j += 256) {
        float v = wr[j];
        if (v != 0.0f) {
            unsigned int b  = (unsigned int)j & 31u;
            unsigned int jb = atomicAdd(&bank_cnt[b], 1u);
            unsigned int g  = jb & 15u;
            unsigned int s  = 0xFFFFFFFFu;
            for (int tries = 0; tries < 16; ++tries) {
                unsigned int cand = atomicAdd(&group_cnt[g], 1u);
                if (cand < 64u) { s = cand; break; }
                g = (g + 1u) & 15u;
            }
            if (s != 0xFFFFFFFFu) {
                unsigned int i = g >> 2, k = g & 3u;
                unsigned int pos = 4u * (i * 64u + s) + k;
                ev[base + pos] = v;
                ec[base + pos] = (unsigned short)j;
            }
        }
    }
}

__device__ __forceinline__ u64t xload(const u64t* p) {
    return __hip_atomic_load(p, __ATOMIC_RELAXED, __HIP_MEMORY_SCOPE_AGENT);
}

__global__ __launch_bounds__(TPB) void esn_step_sparse(
    const float* __restrict__ u, const float* __restrict__ w_in,
    const float* __restrict__ ev, const unsigned short* __restrict__ ec,
    u64t* xp_a, u64t* xp_b, const float* __restrict__ w_eff,
    float* __restrict__ out, int T)
{
    __shared__ float xs[Nn];
    __shared__ float dpart[NWAVES];

    const int tid  = threadIdx.x;
    const int lane = tid & 63;
    const int wave = tid >> 6;
    const int row  = blockIdx.x * ROWS_PER_BLOCK + wave;

    const float wi = w_in[row];
    const float we0 = w_eff[tid];
    const float we1 = w_eff[TPB + tid];
    const float we2 = w_eff[2 * TPB + tid];
    const float we3 = w_eff[3 * TPB + tid];

    // hoist this row's ELL slice into registers (loop-invariant)
    const float4*  v4 = (const float4*)(ev + (size_t)row * ELL_CAP);
    const ushort4* c4 = (const ushort4*)(ec + (size_t)row * ELL_CAP);
    const float4  rv0 = v4[lane],       rv1 = v4[64 + lane],
                  rv2 = v4[128 + lane], rv3 = v4[192 + lane];
    const ushort4 rc0 = c4[lane],       rc1 = c4[64 + lane],
                  rc2 = c4[128 + lane], rc3 = c4[192 + lane];

    u64t* bufs[2] = { xp_a, xp_b };

    for (int t = 0; t <= T; ++t) {
        u64t* xc = bufs[t & 1];
        const unsigned int tg = (unsigned int)t;

        // poll + stage x_t: issue all 4 loads, then spin per word (per-lane)
        u64t w0 = xload(&xc[tid]);
        u64t w1 = xload(&xc[TPB + tid]);
        u64t w2 = xload(&xc[2 * TPB + tid]);
        u64t w3 = xload(&xc[3 * TPB + tid]);
        while ((unsigned int)(w0 >> 32) != tg) w0 = xload(&xc[tid]);
        xs[tid] = __uint_as_float((unsigned int)w0);
        while ((unsigned int)(w1 >> 32) != tg) w1 = xload(&xc[TPB + tid]);
        xs[TPB + tid] = __uint_as_float((unsigned int)w1);
        while ((unsigned int)(w2 >> 32) != tg) w2 = xload(&xc[2 * TPB + tid]);
        xs[2 * TPB + tid] = __uint_as_float((unsigned int)w2);
        while ((unsigned int)(w3 >> 32) != tg) w3 = xload(&xc[3 * TPB + tid]);
        xs[3 * TPB + tid] = __uint_as_float((unsigned int)w3);
        __syncthreads();

        if (t < T) {
            const float ut = u[t];
            float acc = 0.0f;
            acc += rv0.x * xs[rc0.x]; acc += rv0.y * xs[rc0.y];
            acc += rv0.z * xs[rc0.z]; acc += rv0.w * xs[rc0.w];
            acc += rv1.x * xs[rc1.x]; acc += rv1.y * xs[rc1.y];
            acc += rv1.z * xs[rc1.z]; acc += rv1.w * xs[rc1.w];
            acc += rv2.x * xs[rc2.x]; acc += rv2.y * xs[rc2.y];
            acc += rv2.z * xs[rc2.z]; acc += rv2.w * xs[rc2.w];
            acc += rv3.x * xs[rc3.x]; acc += rv3.y * xs[rc3.y];
            acc += rv3.z * xs[rc3.z]; acc += rv3.w * xs[rc3.w];
            #pragma unroll
            for (int off = 32; off > 0; off >>= 1)
                acc += __shfl_xor(acc, off, 64);

            if (lane == 0) {
                float z = __fmaf_rn(wi, ut, acc);
                // tanh(z) = 1 - 2/(exp(2z)+1); exact at +-inf, no cancellation
                float e = __expf(2.0f * z);
                float xnew = 1.0f - 2.0f / (e + 1.0f);
                u64t pw = ((u64t)(unsigned int)(t + 1) << 32) |
                          (u64t)(unsigned int)__float_as_uint(xnew);
                __hip_atomic_store(&bufs[(t + 1) & 1][row], pw,
                                   __ATOMIC_RELAXED, __HIP_MEMORY_SCOPE_AGENT);
            }
        }

        // rotating output dot: xs holds x_t = state after input u[t-1]
        if (t >= WASHOUT_N + 1 && (t & (NBLOCKS - 1)) == blockIdx.x) {
            float d = we0 * xs[tid] + we1 * xs[TPB + tid]
                    + we2 * xs[2 * TPB + tid] + we3 * xs[3 * TPB + tid];
            #pragma unroll
            for (int off = 32; off > 0; off >>= 1)
                d += __shfl_xor(d, off, 64);
            if (lane == 0) dpart[wave] = d;
            __syncthreads();
            if (wave == 0) {
                float s = (lane < NWAVES) ? dpart[lane] : 0.0f;
                #pragma unroll
                for (int off = 8; off > 0; off >>= 1)
                    s += __shfl_xor(s, off, 64);
                if (lane == 0) out[t - WASHOUT_N - 1] = s;
            }
        }

        __syncthreads();   // all xs reads done before next iteration's stage
    }
}

// ---------------- dense fallback (only if ws too small for ELL) -------------
__global__ __launch_bounds__(TPB) void esn_step_dense(
    const float* __restrict__ u, const float* __restrict__ W,
    const float* __restrict__ w_in, float* x_a, float* x_b,
    const float* __restrict__ w_eff, unsigned int* bar,
    float* __restrict__ out, int T)
{
    __shared__ float xs[Nn];
    __shared__ float partial[NWAVES];
    const int tid  = threadIdx.x;
    const int lane = tid & 63;
    const int wave = tid >> 6;
    const int row  = blockIdx.x * ROWS_PER_BLOCK + wave;
    const float wi = w_in[row];
    const float we = w_eff[row];
    unsigned int* bar_count = bar;
    unsigned int* bar_gen   = bar + 32;
    float* xc = x_a;
    float* xn = x_b;
    const float4* wrow = (const float4*)(W + (size_t)row * Nn);

    for (int t = 0; t < T; ++t) {
        float ut = u[t];
        float4 v = ((const float4*)xc)[tid];
        ((float4*)xs)[tid] = v;
        __syncthreads();
        float acc = 0.0f;
        #pragma unroll
        for (int i = 0; i < 16; ++i) {
            float4 wv = wrow[i * 64 + lane];
            float4 xv = ((const float4*)xs)[i * 64 + lane];
            acc += wv.x * xv.x + wv.y * xv.y + wv.z * xv.z + wv.w * xv.w;
        }
        #pragma unroll
        for (int off = 32; off > 0; off >>= 1)
            acc += __shfl_xor(acc, off, 64);
        if (lane == 0) {
            float xnew = tanhf(__fmaf_rn(wi, ut, acc));
            xn[row] = xnew;
            partial[wave] = we * xnew;
        }
        __syncthreads();
        if (tid == 0) {
            if (t >= WASHOUT_N) {
                float s = 0.0f;
                #pragma unroll
                for (int w2 = 0; w2 < NWAVES; ++w2) s += partial[w2];
                atomicAdd(&out[t - WASHOUT_N], s);
            }
            __threadfence();
            unsigned int g = __hip_atomic_load(bar_gen, __ATOMIC_RELAXED,
                                               __HIP_MEMORY_SCOPE_AGENT);
            unsigned int a = __hip_atomic_fetch_add(bar_count, 1u, __ATOMIC_ACQ_REL,
                                                    __HIP_MEMORY_SCOPE_AGENT);
            if (a == NBLOCKS - 1) {
                __hip_atomic_store(bar_count, 0u, __ATOMIC_RELAXED,
                                   __HIP_MEMORY_SCOPE_AGENT);
                __hip_atomic_store(bar_gen, g + 1u, __ATOMIC_RELEASE,
                                   __HIP_MEMORY_SCOPE_AGENT);
            } else {
                while (__hip_atomic_load(bar_gen, __ATOMIC_RELAXED,
                                         __HIP_MEMORY_SCOPE_AGENT) == g) {
                    __builtin_amdgcn_s_sleep(2);
                }
            }
            __threadfence();
        }
        __syncthreads();
        float* tmp = xc; xc = xn; xn = tmp;
    }
}

extern "C" void kernel_launch(void* const* d_in, const int* in_sizes, int n_in,
                              void* d_out, int out_size, void* d_ws, size_t ws_size,
                              hipStream_t stream)
{
    const float* u     = (const float*)d_in[0];
    const float* W     = (const float*)d_in[1];
    const float* w_in  = (const float*)d_in[2];
    const float* w_out = (const float*)d_in[3];
    const int*   mask  = (const int*)d_in[4];
    float* out = (float*)d_out;
    int T = in_sizes[0];

    const size_t ev_bytes  = (size_t)Nn * ELL_CAP * sizeof(float);          // 16 MB
    const size_t ec_bytes  = (size_t)Nn * ELL_CAP * sizeof(unsigned short); // 8 MB
    const size_t aux_bytes = 2 * (Nn * 8) + Nn * 4;                         // 80 KB
    char* ws = (char*)d_ws;

    if (ws_size >= ev_bytes + ec_bytes + aux_bytes) {
        float*          ev    = (float*)(ws);
        unsigned short* ec    = (unsigned short*)(ws + ev_bytes);
        u64t*           xp_a  = (u64t*)(ws + ev_bytes + ec_bytes);
        u64t*           xp_b  = (u64t*)(ws + ev_bytes + ec_bytes + Nn * 8);
        float*          w_eff = (float*)(ws + ev_bytes + ec_bytes + 2 * Nn * 8);

        hipLaunchKernelGGL(esn_init, dim3(16), dim3(256), 0, stream,
                           w_out, mask, xp_a, xp_b, w_eff, out, out_size);
        hipLaunchKernelGGL(build_ell, dim3(Nn), dim3(256), 0, stream, W, ev, ec);

        void* args[] = { (void*)&u, (void*)&w_in, (void*)&ev, (void*)&ec,
                         (void*)&xp_a, (void*)&xp_b, (void*)&w_eff,
                         (void*)&out, (void*)&T };
        hipError_t err = hipLaunchCooperativeKernel((const void*)esn_step_sparse,
                                                    dim3(NBLOCKS), dim3(TPB),
                                                    args, 0, stream);
        if (err != hipSuccess) {
            hipLaunchKernelGGL(esn_step_sparse, dim3(NBLOCKS), dim3(TPB), 0, stream,
                               u, w_in, ev, ec, xp_a, xp_b, w_eff, out, T);
        }
    } else {
        float*        x_a   = (float*)(ws);
        float*        x_b   = (float*)(ws + 16384);
        float*        w_eff2= (float*)(ws + 32768);
        unsigned int* bar   = (unsigned int*)(ws + 49152);
        // reuse esn_init shape: init x buffers as plain floats via memset-like
        // path: esn_init writes tagged zeros (= 0.0f pairs) -- safe for dense
        // kernel too since 0ull overlays two 0.0f floats.
        hipLaunchKernelGGL(esn_init, dim3(16), dim3(256), 0, stream,
                           w_out, mask, (u64t*)x_a, (u64t*)x_b, w_eff2, out,
                           out_size);
        hipMemsetAsync(bar, 0, 256, stream);
        void* args[] = { (void*)&u, (void*)&W, (void*)&w_in, (void*)&x_a,
                         (void*)&x_b, (void*)&w_eff2, (void*)&bar, (void*)&out,
                         (void*)&T };
        hipError_t err = hipLaunchCooperativeKernel((const void*)esn_step_dense,
                                                    dim3(NBLOCKS), dim3(TPB),
                                                    args, 0, stream);
        if (err != hipSuccess) {
            hipLaunchKernelGGL(esn_step_dense, dim3(NBLOCKS), dim3(TPB), 0, stream,
                               u, W, w_in, x_a, x_b, w_eff2, bar, out, T);
        }
    }
}

// Round 5
// 9761.969 us; speedup vs baseline: 6.3864x; 1.8662x over previous
//
#include <hip/hip_runtime.h>
#include <hip/hip_runtime_api.h>
#include <hip/hip_fp16.h>
#include <math.h>

// ESN: x_{t+1} = tanh(w_in * u_t + W @ x_t);  out[t-200] = dot(w_eff, x_{t+1})
//
// R5: - state words are self-validating u32 = (tag16 << 16) | fp16(x).
//       4B atomicity => no value/tag tearing. Two 8B atomic loads cover each
//       thread's 4 contiguous words; failing halves re-polled with s_sleep
//       throttle => poll fabric load drops ~20x.
//     - block publishes its 16 rows as ONE coalesced 64B store (via LDS).
//     - output moved off the hot loop: publish wave appends fp16 x_t to a
//       32 MB history buffer; trailing GEMV kernel computes out = hist @ w_eff.

#define Nn 4096
#define WASHOUT_N 200
#define NBLOCKS 256
#define TPB 1024
#define ROWS_PER_BLOCK 16   // Nn / NBLOCKS
#define NWAVES 16           // TPB / 64
#define ELL_CAP 1024        // 16 gather groups x 64 lanes; mean nnz 819

typedef unsigned long long u64t;
typedef unsigned int u32t;

static __device__ __forceinline__ unsigned short f2h(float f) {
    __half h = __float2half_rn(f);
    union { __half h; unsigned short u; } cv; cv.h = h; return cv.u;
}
static __device__ __forceinline__ float h2f(unsigned short ub) {
    union { __half h; unsigned short u; } cv; cv.u = ub; return __half2float(cv.h);
}

__global__ __launch_bounds__(256) void esn_init(
    const float* __restrict__ w_out, const int* __restrict__ mask,
    u32t* __restrict__ xp_a, u32t* __restrict__ xp_b,
    float* __restrict__ w_eff, float* __restrict__ out, int out_n)
{
    int i = blockIdx.x * blockDim.x + threadIdx.x;
    if (i < Nn) {
        xp_a[i] = 0u;            // tag 0 | fp16(0.0) == x_0
        xp_b[i] = 0xFFFF0000u;   // invalid tag (never matches 1..4096)
        w_eff[mask[i]] = w_out[i];
        if (i < out_n) out[i] = 0.0f;
    }
}

// One block per row. Deal nonzeros into 16 gather-groups; each group is one
// wave-wide LDS gather. Keep <=2 cols per LDS bank per group (2-way is free).
__global__ __launch_bounds__(256) void build_ell(
    const float* __restrict__ W, float* __restrict__ ev,
    unsigned short* __restrict__ ec)
{
    int row = blockIdx.x;
    __shared__ unsigned int bank_cnt[32];
    __shared__ unsigned int group_cnt[16];
    if (threadIdx.x < 32) bank_cnt[threadIdx.x] = 0u;
    if (threadIdx.x < 16) group_cnt[threadIdx.x] = 0u;
    __syncthreads();

    const float* wr = W + (size_t)row * Nn;
    size_t base = (size_t)row * ELL_CAP;

    for (int s = threadIdx.x; s < ELL_CAP; s += 256) {
        ev[base + s] = 0.0f;
        ec[base + s] = 0;               // col 0 -> broadcast, free
    }
    __syncthreads();

    for (int j = threadIdx.x; j < Nn; j += 256) {
        float v = wr[j];
        if (v != 0.0f) {
            unsigned int b  = (unsigned int)j & 31u;
            unsigned int jb = atomicAdd(&bank_cnt[b], 1u);
            unsigned int g  = jb & 15u;
            unsigned int s  = 0xFFFFFFFFu;
            for (int tries = 0; tries < 16; ++tries) {
                unsigned int cand = atomicAdd(&group_cnt[g], 1u);
                if (cand < 64u) { s = cand; break; }
                g = (g + 1u) & 15u;
            }
            if (s != 0xFFFFFFFFu) {
                unsigned int i = g >> 2, k = g & 3u;
                unsigned int pos = 4u * (i * 64u + s) + k;
                ev[base + pos] = v;
                ec[base + pos] = (unsigned short)j;
            }
        }
    }
}

__device__ __forceinline__ u64t xload64(const u64t* p) {
    return __hip_atomic_load(p, __ATOMIC_RELAXED, __HIP_MEMORY_SCOPE_AGENT);
}

__global__ __launch_bounds__(TPB) void esn_step_sparse(
    const float* __restrict__ u, const float* __restrict__ w_in,
    const float* __restrict__ ev, const unsigned short* __restrict__ ec,
    u32t* xp_a, u32t* xp_b, const float* __restrict__ w_eff,
    unsigned short* __restrict__ hist, float* __restrict__ out, int T)
{
    __shared__ __align__(16) float xs[Nn];
    __shared__ u32t  xpub[NWAVES];
    __shared__ float dpart[NWAVES];

    const int tid  = threadIdx.x;
    const int lane = tid & 63;
    const int wave = tid >> 6;
    const int base_row = blockIdx.x * ROWS_PER_BLOCK;
    const int row  = base_row + wave;

    const float wi = w_in[row];
    // only used in the no-hist fallback dot
    const float we0 = w_eff[tid];
    const float we1 = w_eff[TPB + tid];
    const float we2 = w_eff[2 * TPB + tid];
    const float we3 = w_eff[3 * TPB + tid];

    // hoist this row's ELL slice into registers (loop-invariant)
    const float4*  v4 = (const float4*)(ev + (size_t)row * ELL_CAP);
    const ushort4* c4 = (const ushort4*)(ec + (size_t)row * ELL_CAP);
    const float4  rv0 = v4[lane],       rv1 = v4[64 + lane],
                  rv2 = v4[128 + lane], rv3 = v4[192 + lane];
    const ushort4 rc0 = c4[lane],       rc1 = c4[64 + lane],
                  rc2 = c4[128 + lane], rc3 = c4[192 + lane];

    u32t* bufs[2] = { xp_a, xp_b };
    const bool have_hist = (hist != nullptr);

    for (int t = 0; t <= T; ++t) {
        if (t == T && have_hist) break;   // tail iter only needed for in-loop dot

        u32t* xc = bufs[t & 1];
        const u64t tg = (u64t)(u32t)t;
        const float ut = (t < T) ? u[t] : 0.0f;

        // ---- poll own 4 contiguous words (2 x 8B), predicated + throttled ----
        const u64t* p = (const u64t*)xc + 2 * tid;
        u64t a = xload64(p);
        u64t b = xload64(p + 1);
        for (;;) {
            bool okA = (((a >> 16) & 0xFFFFull) == tg) && ((a >> 48) == tg);
            bool okB = (((b >> 16) & 0xFFFFull) == tg) && ((b >> 48) == tg);
            if (okA && okB) break;
            __builtin_amdgcn_s_sleep(1);
            if (!okA) a = xload64(p);
            if (!okB) b = xload64(p + 1);
        }
        // extract fp16 values, stage 4 floats with one ds_write_b128
        ((float4*)xs)[tid] = make_float4(
            h2f((unsigned short)(a & 0xFFFF)),
            h2f((unsigned short)((a >> 32) & 0xFFFF)),
            h2f((unsigned short)(b & 0xFFFF)),
            h2f((unsigned short)((b >> 32) & 0xFFFF)));
        __syncthreads();

        // ---- row update ----
        if (t < T) {
            float acc = 0.0f;
            acc += rv0.x * xs[rc0.x]; acc += rv0.y * xs[rc0.y];
            acc += rv0.z * xs[rc0.z]; acc += rv0.w * xs[rc0.w];
            acc += rv1.x * xs[rc1.x]; acc += rv1.y * xs[rc1.y];
            acc += rv1.z * xs[rc1.z]; acc += rv1.w * xs[rc1.w];
            acc += rv2.x * xs[rc2.x]; acc += rv2.y * xs[rc2.y];
            acc += rv2.z * xs[rc2.z]; acc += rv2.w * xs[rc2.w];
            acc += rv3.x * xs[rc3.x]; acc += rv3.y * xs[rc3.y];
            acc += rv3.z * xs[rc3.z]; acc += rv3.w * xs[rc3.w];
            #pragma unroll
            for (int off = 32; off > 0; off >>= 1)
                acc += __shfl_xor(acc, off, 64);

            if (lane == 0) {
                float z = __fmaf_rn(wi, ut, acc);
                float e = __expf(2.0f * z);               // tanh via exp
                float xnew = 1.0f - 2.0f / (e + 1.0f);
                xpub[wave] = ((u32t)(t + 1) << 16) | (u32t)f2h(xnew);
            }
        }

        // ---- fallback in-loop output dot (no hist buffer) ----
        const bool des = (!have_hist) && (t >= WASHOUT_N + 1) &&
                         ((t & (NBLOCKS - 1)) == (int)blockIdx.x);
        if (des) {
            float d = we0 * xs[tid] + we1 * xs[TPB + tid]
                    + we2 * xs[2 * TPB + tid] + we3 * xs[3 * TPB + tid];
            #pragma unroll
            for (int off = 32; off > 0; off >>= 1)
                d += __shfl_xor(d, off, 64);
            if (lane == 0) dpart[wave] = d;
        }
        __syncthreads();

        // ---- coalesced publish by wave 0 (one 64B line) + hist append ----
        if (wave == 0) {
            if (t < T && lane < ROWS_PER_BLOCK) {
                u32t w = xpub[lane];
                __hip_atomic_store(&bufs[(t + 1) & 1][base_row + lane], w,
                                   __ATOMIC_RELAXED, __HIP_MEMORY_SCOPE_AGENT);
                if (have_hist)
                    hist[(size_t)t * Nn + base_row + lane] =
                        (unsigned short)(w & 0xFFFF);
            }
            if (des) {
                float s = (lane < NWAVES) ? dpart[lane] : 0.0f;
                #pragma unroll
                for (int off = 8; off > 0; off >>= 1)
                    s += __shfl_xor(s, off, 64);
                if (lane == 0) out[t - WASHOUT_N - 1] = s;
            }
        }
        // no trailing barrier needed: all xs reads happen before the barrier
        // above; next iteration's stage only writes each thread's own chunk,
        // and gathers are gated by the post-stage barrier.
    }
}

// out[k] = dot(w_eff, hist[k + WASHOUT_N])  -- one block per output element
__global__ __launch_bounds__(256) void esn_out_gemv(
    const unsigned short* __restrict__ hist, const float* __restrict__ w_eff,
    float* __restrict__ out, int n_out)
{
    __shared__ float swave[4];
    int k = blockIdx.x;
    if (k >= n_out) return;
    const __half2* hp = (const __half2*)(hist + (size_t)(k + WASHOUT_N) * Nn);
    const int tid = threadIdx.x;
    float acc = 0.0f;
    #pragma unroll
    for (int j = tid; j < Nn / 2; j += 256) {
        float2 xv = __half22float2(hp[j]);
        acc += w_eff[2 * j] * xv.x + w_eff[2 * j + 1] * xv.y;
    }
    #pragma unroll
    for (int off = 32; off > 0; off >>= 1)
        acc += __shfl_xor(acc, off, 64);
    if ((tid & 63) == 0) swave[tid >> 6] = acc;
    __syncthreads();
    if (tid == 0) out[k] = swave[0] + swave[1] + swave[2] + swave[3];
}

extern "C" void kernel_launch(void* const* d_in, const int* in_sizes, int n_in,
                              void* d_out, int out_size, void* d_ws, size_t ws_size,
                              hipStream_t stream)
{
    const float* u     = (const float*)d_in[0];
    const float* W     = (const float*)d_in[1];
    const float* w_in  = (const float*)d_in[2];
    const float* w_out = (const float*)d_in[3];
    const int*   mask  = (const int*)d_in[4];
    float* out = (float*)d_out;
    int T = in_sizes[0];

    const size_t ev_bytes   = (size_t)Nn * ELL_CAP * sizeof(float);          // 16 MB
    const size_t ec_bytes   = (size_t)Nn * ELL_CAP * sizeof(unsigned short); // 8 MB
    const size_t hist_bytes = (size_t)Nn * Nn * sizeof(unsigned short);      // 32 MB
    const size_t aux_bytes  = 64 * 1024;
    char* ws = (char*)d_ws;

    const bool fits_hist = ws_size >= ev_bytes + ec_bytes + hist_bytes + aux_bytes;
    const bool fits_ell  = ws_size >= ev_bytes + ec_bytes + aux_bytes;

    if (fits_ell) {
        size_t off = ev_bytes + ec_bytes;
        float*          ev    = (float*)(ws);
        unsigned short* ec    = (unsigned short*)(ws + ev_bytes);
        unsigned short* hist  = fits_hist ? (unsigned short*)(ws + off) : nullptr;
        if (fits_hist) off += hist_bytes;
        u32t*           xp_a  = (u32t*)(ws + off);
        u32t*           xp_b  = (u32t*)(ws + off + 16384);
        float*          w_eff = (float*)(ws + off + 32768);

        hipLaunchKernelGGL(esn_init, dim3(16), dim3(256), 0, stream,
                           w_out, mask, xp_a, xp_b, w_eff, out, out_size);
        hipLaunchKernelGGL(build_ell, dim3(Nn), dim3(256), 0, stream, W, ev, ec);

        void* args[] = { (void*)&u, (void*)&w_in, (void*)&ev, (void*)&ec,
                         (void*)&xp_a, (void*)&xp_b, (void*)&w_eff,
                         (void*)&hist, (void*)&out, (void*)&T };
        hipError_t err = hipLaunchCooperativeKernel((const void*)esn_step_sparse,
                                                    dim3(NBLOCKS), dim3(TPB),
                                                    args, 0, stream);
        if (err != hipSuccess) {
            hipLaunchKernelGGL(esn_step_sparse, dim3(NBLOCKS), dim3(TPB), 0, stream,
                               u, w_in, ev, ec, xp_a, xp_b, w_eff, hist, out, T);
        }
        if (fits_hist) {
            hipLaunchKernelGGL(esn_out_gemv, dim3(out_size), dim3(256), 0, stream,
                               hist, w_eff, out, out_size);
        }
    }
    // (ws always >= 24 MB in this harness; no dense fallback path retained)
}